// Round 6
// baseline (60.675 us; speedup 1.0000x reference)
//
#include <hip/hip_runtime.h>

#define H_DIM 3072
#define W_DIM 3072
#define TW 32
#define TH 32
#define BB_ROWS 42     // 31*(cos+sin) <= 39.73 for theta in [0, 20deg] -> +2
#define BB_STRIDE 132  // floats/row: 42 cols * 3 = 126 + 6 zero-pad; 132*4B=528B = 33*16B
                       // (keeps ds_write_b128 aligned); 132 mod 32 = 4 spreads banks

typedef float f32x4 __attribute__((ext_vector_type(4)));
typedef f32x4 __attribute__((aligned(4))) f32x4u;  // global tap/segment bases are 4B-aligned

__global__ __launch_bounds__(256) void rotation_kernel(
    const float* __restrict__ img,     // (H, W, 3) f32
    const float* __restrict__ fv,      // (1,) f32
    float* __restrict__ out)           // (H, W, 3) f32
{
    __shared__ __attribute__((aligned(16))) float S[BB_ROWS * BB_STRIDE];  // 22,176 B

    const int tx = threadIdx.x;   // 0..7  : 4 consecutive px each
    const int ty = threadIdx.y;   // 0..31 : output row in tile
    const int C0 = blockIdx.x * TW;
    const int R0 = blockIdx.y * TH;

    const float theta = fv[0] * 20.0f * (3.14159265358979323846f / 180.0f);
    const float ct = __cosf(theta);   // theta in [0,0.349]: HW trig error ~1e-6,
    const float st = __sinf(theta);   // verified absmax identical to libm (R5)

    const float o_r = (float)H_DIM / 2.0f + 0.5f;
    const float o_c = (float)W_DIM / 2.0f + 0.5f;

    // ---- block-uniform bbox from the 4 tile corners (affine -> corner extrema) ----
    const float drA = (float)R0 - o_r, drB = (float)(R0 + TH - 1) - o_r;
    const float dcA = (float)C0 - o_c, dcB = (float)(C0 + TW - 1) - o_c;
    float min_r = 1e30f, max_r = -1e30f, min_c = 1e30f, max_c = -1e30f;
    #pragma unroll
    for (int k = 0; k < 4; ++k) {
        const float dr = (k & 1) ? drB : drA;
        const float dc = (k & 2) ? dcB : dcA;
        const float sr = ct * dr - st * dc + o_r;
        const float sc = st * dr + ct * dc + o_c;
        min_r = fminf(min_r, sr); max_r = fmaxf(max_r, sr);
        min_c = fminf(min_c, sc); max_c = fmaxf(max_c, sc);
    }
    // interior <=> every tap index computed without any clamp stays in-image
    const bool interior = (min_r >= 1.0f) & (max_r <= (float)(H_DIM - 2)) &
                          (min_c >= 1.0f) & (max_c <= (float)(W_DIM - 2));

    const int r_lo = min(max((int)floorf(min_r), 0), H_DIM - 1);
    const int c_lo = min(max((int)floorf(min_c), 0), W_DIM - 1);
    const int r_hi = min(min(max((int)floorf(max_r), 0), H_DIM - 1) + 1, H_DIM - 1);
    const int c_hi = min(min(max((int)floorf(max_c), 0), W_DIM - 1) + 1, W_DIM - 1);
    const int nrows = r_hi - r_lo + 1;          // <= 42
    const int nflt  = (c_hi - c_lo + 1) * 3;    // <= 126
    const int nflt4 = nflt >> 2;
    const int rem   = nflt & 3;

    // ---- stage bbox: dense global x4 reads -> aligned ds_write_b128 ----
    for (int yy = ty; yy < nrows; yy += 32) {
        const float* src = img + ((size_t)(r_lo + yy) * W_DIM + c_lo) * 3;
        float* dst = S + yy * BB_STRIDE;
        for (int xx = tx; xx < nflt4; xx += 8) {
            const f32x4u v = *(const f32x4u*)(src + xx * 4);
            *(f32x4*)(dst + xx * 4) = v;       // byte 528*yy + 16*xx: 16B-aligned
        }
        if (tx < rem) dst[nflt4 * 4 + tx] = src[nflt4 * 4 + tx];
        if (tx < 6)   dst[nflt + tx] = 0.0f;   // degenerate-border windows read zeros
    }
    __syncthreads();

    // ---- gather ----
    const int r = R0 + ty;
    const float drr = (float)r - o_r;
    const int K = r_lo * BB_STRIDE + c_lo * 3;
    // coords for p=0; per-px increments: d(src_r)/dc = -st, d(src_c)/dc = +ct
    const int cbase = C0 + tx * 4;
    float sr0 = ct * drr - st * ((float)cbase - o_c) + o_r;
    float sc0 = st * drr + ct * ((float)cbase - o_c) + o_c;

    float res[12];

    if (interior) {
        #pragma unroll
        for (int p = 0; p < 4; ++p) {
            const float src_r = sr0 - st * (float)p;
            const float src_c = sc0 + ct * (float)p;
            const float r0f = floorf(src_r);
            const float c0f = floorf(src_c);
            const float wr = src_r - r0f;
            const float wc = src_c - c0f;
            const int addr = (int)r0f * BB_STRIDE + (int)c0f * 3 - K;
            const float* s0 = S + addr;          // px c0 | px c1 : floats 0..5
            const float* s1 = s0 + BB_STRIDE;    // r1 = r0+1, always staged
            #pragma unroll
            for (int ch = 0; ch < 3; ++ch) {
                const float row0 = s0[ch] + wc * (s0[3 + ch] - s0[ch]);
                const float row1 = s1[ch] + wc * (s1[3 + ch] - s1[ch]);
                res[p * 3 + ch] = row0 + wr * (row1 - row0);
            }
        }
    } else {
        #pragma unroll
        for (int p = 0; p < 4; ++p) {
            float src_r = sr0 - st * (float)p;
            float src_c = sc0 + ct * (float)p;
            src_r = fminf(fmaxf(src_r, 0.0f), (float)(H_DIM - 1));
            src_c = fminf(fmaxf(src_c, 0.0f), (float)(W_DIM - 1));
            const float r0f = floorf(src_r);
            const float c0f = floorf(src_c);
            const float wr = src_r - r0f;
            const float wc = src_c - c0f;
            const int r0 = (int)r0f;
            const int c0 = (int)c0f;
            const int r1 = min(r0 + 1, H_DIM - 1);
            int cb = max(min(c0, c_hi - 1), c_lo);   // 2-col window base in staged range
            const bool hi = (c0 > cb);               // c0 clamped at right edge: wc==0
            const int ly0 = min(max(r0 - r_lo, 0), BB_ROWS - 1);
            const int ly1 = min(max(r1 - r_lo, 0), BB_ROWS - 1);
            const int lx  = min(max((cb - c_lo) * 3, 0), BB_STRIDE - 6);
            const float* s0 = S + ly0 * BB_STRIDE + lx;
            const float* s1 = S + ly1 * BB_STRIDE + lx;
            float q00 = s0[0], q01 = s0[1], q02 = s0[2], q03 = s0[3], q04 = s0[4], q05 = s0[5];
            float q10 = s1[0], q11 = s1[1], q12 = s1[2], q13 = s1[3], q14 = s1[4], q15 = s1[5];
            if (hi) { q00 = q03; q01 = q04; q02 = q05; q10 = q13; q11 = q14; q12 = q15; }
            float row0, row1;
            row0 = q00 + wc * (q03 - q00); row1 = q10 + wc * (q13 - q10);
            res[p * 3 + 0] = row0 + wr * (row1 - row0);
            row0 = q01 + wc * (q04 - q01); row1 = q11 + wc * (q14 - q11);
            res[p * 3 + 1] = row0 + wr * (row1 - row0);
            row0 = q02 + wc * (q05 - q02); row1 = q12 + wc * (q15 - q12);
            res[p * 3 + 2] = row0 + wr * (row1 - row0);
        }
    }

    // 48 contiguous bytes/thread, 16B-aligned: 3x dwordx4 stores
    float4* op = (float4*)(out + ((size_t)r * W_DIM + cbase) * 3);
    op[0] = make_float4(res[0], res[1], res[2],  res[3]);
    op[1] = make_float4(res[4], res[5], res[6],  res[7]);
    op[2] = make_float4(res[8], res[9], res[10], res[11]);
}

extern "C" void kernel_launch(void* const* d_in, const int* in_sizes, int n_in,
                              void* d_out, int out_size, void* d_ws, size_t ws_size,
                              hipStream_t stream) {
    const float* img = (const float*)d_in[0];
    const float* fv  = (const float*)d_in[1];
    float* out = (float*)d_out;

    dim3 block(8, 32, 1);
    dim3 grid(W_DIM / TW, H_DIM / TH, 1);
    rotation_kernel<<<grid, block, 0, stream>>>(img, fv, out);
}

// Round 8
// 57.967 us; speedup vs baseline: 1.0467x; 1.0467x over previous
//
#include <hip/hip_runtime.h>

#define H_DIM 3072
#define W_DIM 3072
#define TW 32   // tile width  (px) — block(8,32), 4 px/thread
#define TH 32   // tile height (px); wave = 8tx x 8ty = 32x8 px patch

// 4B-aligned vector types: tap base addrs ((r*W+c)*3 floats) are only 4B-aligned.
typedef float f32x4 __attribute__((ext_vector_type(4)));
typedef float f32x2 __attribute__((ext_vector_type(2)));
typedef f32x4 __attribute__((aligned(4))) f32x4u;
typedef f32x2 __attribute__((aligned(4))) f32x2u;

__global__ __launch_bounds__(256) void rotation_kernel(
    const float* __restrict__ img,     // (H, W, 3) f32
    const float* __restrict__ fv,      // (1,) f32
    float* __restrict__ out)           // (H, W, 3) f32
{
    const int tx = threadIdx.x;        // 0..7
    const int ty = threadIdx.y;        // 0..31
    const int C0 = blockIdx.x * TW;
    const int R0 = blockIdx.y * TH;

    // theta in [0, 0.349] rad; HW trig: absmax identical to libm (R5 evidence)
    const float theta = fv[0] * 20.0f * (3.14159265358979323846f / 180.0f);
    const float ct = __cosf(theta);
    const float st = __sinf(theta);

    const float o_r = (float)H_DIM / 2.0f + 0.5f;
    const float o_c = (float)W_DIM / 2.0f + 0.5f;

    // ---- block-uniform interior test from the 4 tile corners ----
    const float drA = (float)R0 - o_r, drB = (float)(R0 + TH - 1) - o_r;
    const float dcA = (float)C0 - o_c, dcB = (float)(C0 + TW - 1) - o_c;
    float min_r = 1e30f, max_r = -1e30f, min_c = 1e30f, max_c = -1e30f;
    #pragma unroll
    for (int k = 0; k < 4; ++k) {
        const float dr = (k & 1) ? drB : drA;
        const float dc = (k & 2) ? dcB : dcA;
        const float sr = ct * dr - st * dc + o_r;
        const float sc = st * dr + ct * dc + o_c;
        min_r = fminf(min_r, sr); max_r = fmaxf(max_r, sr);
        min_c = fminf(min_c, sc); max_c = fmaxf(max_c, sc);
    }
    // margin 0.01 guards corner-vs-per-px fp rounding differences (~1e-4)
    const bool interior = (min_r > 0.01f) & (max_r < (float)(H_DIM - 2) - 0.01f) &
                          (min_c > 0.01f) & (max_c < (float)(W_DIM - 2) - 0.01f);

    const int r = R0 + ty;
    const int cbase = C0 + tx * 4;
    const float drr = (float)r - o_r;
    // p=0 coords; per-px: d(src_r)/dc = -st, d(src_c)/dc = +ct
    const float sr0 = ct * drr - st * ((float)cbase - o_c) + o_r;
    const float sc0 = st * drr + ct * ((float)cbase - o_c) + o_c;

    float wrv[4], wcv[4];
    bool  hiv[4];
    const float* rp0[4];
    const float* rp1[4];

    if (interior) {
        #pragma unroll
        for (int p = 0; p < 4; ++p) {
            const float src_r = sr0 - st * (float)p;
            const float src_c = sc0 + ct * (float)p;
            const float r0f = floorf(src_r);
            const float c0f = floorf(src_c);
            wrv[p] = src_r - r0f;
            wcv[p] = src_c - c0f;
            hiv[p] = false;
            const int idx = (int)r0f * W_DIM + (int)c0f;   // r0<=H-2, c0<=W-2
            rp0[p] = img + (size_t)idx * 3;
            rp1[p] = img + (size_t)(idx + W_DIM) * 3;
        }
    } else {
        #pragma unroll
        for (int p = 0; p < 4; ++p) {
            float src_r = sr0 - st * (float)p;
            float src_c = sc0 + ct * (float)p;
            src_r = fminf(fmaxf(src_r, 0.0f), (float)(H_DIM - 1));
            src_c = fminf(fmaxf(src_c, 0.0f), (float)(W_DIM - 1));
            const float r0f = floorf(src_r);
            const float c0f = floorf(src_c);
            wrv[p] = src_r - r0f;
            wcv[p] = src_c - c0f;
            const int r0 = (int)r0f;
            const int c0 = (int)c0f;
            const int r1 = min(r0 + 1, H_DIM - 1);
            const int cb = min(c0, W_DIM - 2);   // 6-float segment stays in-bounds
            hiv[p] = (c0 > cb);                  // only when c0==W-1 (wc==0 there)
            rp0[p] = img + ((size_t)r0 * W_DIM + cb) * 3;
            rp1[p] = img + ((size_t)r1 * W_DIM + cb) * 3;
        }
    }

    // ---- issue all 16 segment loads back-to-back ----
    f32x4u A0[4], A1[4];
    f32x2u B0[4], B1[4];
    #pragma unroll
    for (int p = 0; p < 4; ++p) {
        A0[p] = *(const f32x4u*)rp0[p];
        B0[p] = *(const f32x2u*)(rp0[p] + 4);
        A1[p] = *(const f32x4u*)rp1[p];
        B1[p] = *(const f32x2u*)(rp1[p] + 4);
    }

    // ---- blend ----
    float res[12];
    #pragma unroll
    for (int p = 0; p < 4; ++p) {
        const float q0[6] = {A0[p][0], A0[p][1], A0[p][2], A0[p][3], B0[p][0], B0[p][1]};
        const float q1[6] = {A1[p][0], A1[p][1], A1[p][2], A1[p][3], B1[p][0], B1[p][1]};
        const float wr = wrv[p], wc = wcv[p];
        const bool hi = hiv[p];
        #pragma unroll
        for (int ch = 0; ch < 3; ++ch) {
            const float t00 = hi ? q0[3 + ch] : q0[ch];
            const float t10 = hi ? q1[3 + ch] : q1[ch];
            const float row0 = t00 + wc * (q0[3 + ch] - t00);
            const float row1 = t10 + wc * (q1[3 + ch] - t10);
            res[p * 3 + ch] = row0 + wr * (row1 - row0);
        }
    }

    // 48 contiguous bytes/thread, 16B-aligned; nontemporal: output is never
    // re-read — keep the write stream from evicting gather lines in L2.
    // (ext_vector f32x4, not HIP float4: builtin requires scalar/vector ptr.)
    f32x4* op = (f32x4*)(out + ((size_t)r * W_DIM + cbase) * 3);
    const f32x4 v0 = {res[0], res[1], res[2],  res[3]};
    const f32x4 v1 = {res[4], res[5], res[6],  res[7]};
    const f32x4 v2 = {res[8], res[9], res[10], res[11]};
    __builtin_nontemporal_store(v0, op + 0);
    __builtin_nontemporal_store(v1, op + 1);
    __builtin_nontemporal_store(v2, op + 2);
}

extern "C" void kernel_launch(void* const* d_in, const int* in_sizes, int n_in,
                              void* d_out, int out_size, void* d_ws, size_t ws_size,
                              hipStream_t stream) {
    const float* img = (const float*)d_in[0];
    const float* fv  = (const float*)d_in[1];
    float* out = (float*)d_out;

    dim3 block(8, 32, 1);
    dim3 grid(W_DIM / TW, H_DIM / TH, 1);
    rotation_kernel<<<grid, block, 0, stream>>>(img, fv, out);
}